// Round 10
// baseline (257.884 us; speedup 1.0000x reference)
//
#include <hip/hip_runtime.h>
#include <hip/hip_bf16.h>
#include <math.h>

#define TV_ 1600
#define SCALE_K 2.885390081777927f   // 2*log2(e): folded into fk/pk rows so tanh uses exp2 directly
#define RS2_ 0.70710678118654752f    // DKH^-0.5 folded into fq/pq rows

typedef __attribute__((ext_vector_type(8))) short bf16x8;
typedef __attribute__((ext_vector_type(4))) float f32x4;
typedef __attribute__((ext_vector_type(2))) __fp16 h2f;

__device__ __forceinline__ float tanh_scaled(float y) {
    y = fminf(44.f, fmaxf(-44.f, y));
    float e = __builtin_amdgcn_exp2f(y);
    float r = __builtin_amdgcn_rcpf(e + 1.f);
    return __builtin_fmaf(e, r, -r);
}

__device__ __forceinline__ ushort f2bf(float f) {
    __hip_bfloat16 h = __float2bfloat16(f);
    return *(ushort*)&h;
}

// ---------------------------------------------------------------------------
// transpose (+ folded prep): blockIdx.x<25: xt/yt bf16 [n][tv][ci] planes +
// se[n][c] += sum_tv x for ALL 64 channels. blockIdx.x==25: prep slice.
// ---------------------------------------------------------------------------
__global__ __launch_bounds__(256) void transpose_kernel(
    const float* __restrict__ x, const float* __restrict__ pe,
    const float* __restrict__ dbg, const float* __restrict__ dbb,
    const float* __restrict__ tcn_w, const float* __restrict__ tg,
    const float* __restrict__ qkv_w, const float* __restrict__ qkv_b,
    ushort* __restrict__ xt, ushort* __restrict__ yt, float* __restrict__ se,
    ushort* __restrict__ wb, ushort* __restrict__ wq, float* __restrict__ qb)
{
    const int tid = threadIdx.x;
    if (blockIdx.x == 25) {
        // prep slice: 64 y-blocks x 514 elems cover 32848
        for (int i = tid; i < 514; i += 256) {
            int idx = blockIdx.y * 514 + i;
            if (idx < 27648) {
                int oc = idx / 576, kk = idx - oc * 576;
                int kt = kk >> 6, ci = kk & 63;
                float a = tg[oc] * rsqrtf(1.f + 1e-5f);
                wb[idx] = f2bf(tcn_w[(oc * 64 + ci) * 9 + kt] * a);
            } else if (idx < 32768) {
                int i2 = idx - 27648;
                int r = i2 >> 6, c = i2 & 63;
                int src; float sc;
                if (r < 16)      { src = r;      sc = RS2_; }
                else if (r < 32) { src = r;      sc = SCALE_K; }
                else if (r < 48) { src = r + 16; sc = 1.f; }
                else if (r < 64) { src = r - 48; sc = RS2_; }
                else             { src = r - 48; sc = SCALE_K; }
                wq[i2] = f2bf(qkv_w[src * 64 + c] * sc);
            } else if (idx < 32848) {
                int r = idx - 32768;
                int src; float sc;
                if (r < 16)      { src = r;      sc = RS2_; }
                else if (r < 32) { src = r;      sc = SCALE_K; }
                else if (r < 48) { src = r + 16; sc = 1.f; }
                else if (r < 64) { src = r - 48; sc = RS2_; }
                else             { src = r - 48; sc = SCALE_K; }
                qb[r] = qkv_b[src] * sc;
            }
        }
        return;
    }

    __shared__ ushort smt[2 * 64 * 66];     // xu @0, yu @4224
    const int tv0 = blockIdx.x * 64;
    const int n = blockIdx.y;
    const int tvl = tid & 63, cig = tid >> 6;
    const int tv = tv0 + tvl;
    const int v = tv % 25;
    const float rs = rsqrtf(1.f + 1e-5f);

    float psum[16];
    #pragma unroll
    for (int k = 0; k < 16; ++k) psum[k] = 0.f;
    #pragma unroll
    for (int k = 0; k < 16; ++k) {
        int ci = k * 4 + cig;
        float xv = x[(n * 64 + ci) * TV_ + tv];
        smt[tvl * 66 + ci] = f2bf(xv * (dbg[ci * 25 + v] * rs) + dbb[ci * 25 + v]);
        smt[4224 + tvl * 66 + ci] = f2bf(xv + pe[ci * TV_ + tv]);
        psum[k] += xv;
    }
    #pragma unroll
    for (int k = 0; k < 16; ++k) {
        float s = psum[k];
        #pragma unroll
        for (int off = 32; off >= 1; off >>= 1) s += __shfl_down(s, off, 64);
        if (tvl == 0) atomicAdd(&se[n * 64 + k * 4 + cig], s);
    }
    __syncthreads();

    #pragma unroll
    for (int j = 0; j < 16; ++j) {
        int chunk = tid + j * 256;
        int plane = chunk >> 11;
        int rr = chunk & 2047;
        int tvr = rr >> 5, p = rr & 31;
        uint val = *(const uint*)&smt[plane * 4224 + tvr * 66 + p * 2];
        ushort* dst = plane ? yt : xt;
        *(uint*)&dst[(n * TV_ + tv0 + tvr) * 64 + p * 2] = val;
    }
}

// ---------------------------------------------------------------------------
// K1: score kernel per (n,v) — unchanged from round 9 (61 us, isolated).
// ---------------------------------------------------------------------------
__global__ __launch_bounds__(256, 5) void score_kernel(
    const ushort* __restrict__ xt, const ushort* __restrict__ yt,
    const ushort* __restrict__ wq, const float* __restrict__ qb,
    const float* __restrict__ attn_w, const float* __restrict__ attn_b,
    float* __restrict__ aoc, float* __restrict__ se)
{
    __shared__ float sm[5312];
    ushort* smu = (ushort*)sm;
    const int MU_ = 1056, AO = 1120;
    const int FKP = 2400, PKP = 2976, FVP = 3552, PQP = 4128, FQP = 4704;

    const int b = blockIdx.x;
    const int l = b >> 3;
    const int n = (b & 7) * 8 + l / 25;
    const int v = l % 25;
    const int tid = threadIdx.x;

    const int lane = tid & 63, wave = tid >> 6;
    const int m16 = lane & 15, q = lane >> 4;

    #pragma unroll
    for (int j = 0; j < 4; ++j) {
        int chunk = tid + j * 256;
        int plane = chunk >> 9;
        int rr = chunk & 511;
        int t = rr >> 3, part = rr & 7;
        const ushort* src = plane ? yt : xt;
        uint4 val = *(const uint4*)&src[(n * TV_ + t * 25 + v) * 64 + part * 8];
        *(uint4*)&smu[plane * 4608 + t * 72 + part * 8] = val;
    }
    __syncthreads();

    f32x4 acc[5];
    #pragma unroll
    for (int mt = 0; mt < 5; ++mt) acc[mt] = (f32x4){0.f, 0.f, 0.f, 0.f};
    #pragma unroll
    for (int kt = 0; kt < 2; ++kt) {
        const int koff = kt * 32 + q * 8;
        bf16x8 bx = *(const bf16x8*)&smu[(wave * 16 + m16) * 72 + koff];
        bf16x8 by = *(const bf16x8*)&smu[4608 + (wave * 16 + m16) * 72 + koff];
        #pragma unroll
        for (int mt = 0; mt < 5; ++mt) {
            bf16x8 a = *(const bf16x8*)&wq[(mt * 16 + m16) * 64 + koff];
            acc[mt] = __builtin_amdgcn_mfma_f32_16x16x32_bf16(a, (mt < 3) ? bx : by, acc[mt], 0, 0, 0);
        }
    }
    __syncthreads();

    {
        const int t = wave * 16 + m16;
        #pragma unroll
        for (int r = 0; r < 4; ++r)
            sm[(q * 4 + r) * 66 + t] = acc[0][r] + qb[q * 4 + r];
        *(h2f*)&sm[FKP + t * 9 + 2 * q] =
            __builtin_amdgcn_cvt_pkrtz(acc[1][0] + qb[16 + q * 4], acc[1][1] + qb[16 + q * 4 + 1]);
        *(h2f*)&sm[FKP + t * 9 + 2 * q + 1] =
            __builtin_amdgcn_cvt_pkrtz(acc[1][2] + qb[16 + q * 4 + 2], acc[1][3] + qb[16 + q * 4 + 3]);
        *(h2f*)&sm[FVP + t * 9 + 2 * q] =
            __builtin_amdgcn_cvt_pkrtz(acc[2][0] + qb[32 + q * 4], acc[2][1] + qb[32 + q * 4 + 1]);
        *(h2f*)&sm[FVP + t * 9 + 2 * q + 1] =
            __builtin_amdgcn_cvt_pkrtz(acc[2][2] + qb[32 + q * 4 + 2], acc[2][3] + qb[32 + q * 4 + 3]);
        *(h2f*)&sm[PQP + t * 9 + 2 * q] =
            __builtin_amdgcn_cvt_pkrtz(acc[3][0] + qb[48 + q * 4], acc[3][1] + qb[48 + q * 4 + 1]);
        *(h2f*)&sm[PQP + t * 9 + 2 * q + 1] =
            __builtin_amdgcn_cvt_pkrtz(acc[3][2] + qb[48 + q * 4 + 2], acc[3][3] + qb[48 + q * 4 + 3]);
        *(h2f*)&sm[PKP + t * 9 + 2 * q] =
            __builtin_amdgcn_cvt_pkrtz(acc[4][0] + qb[64 + q * 4], acc[4][1] + qb[64 + q * 4 + 1]);
        *(h2f*)&sm[PKP + t * 9 + 2 * q + 1] =
            __builtin_amdgcn_cvt_pkrtz(acc[4][2] + qb[64 + q * 4 + 2], acc[4][3] + qb[64 + q * 4 + 3]);
    }
    __syncthreads();

    if (tid < 64) {
        int ch = tid & 15, qq = tid >> 4;
        float s = 0.f;
        #pragma unroll
        for (int t = 0; t < 16; ++t) s += sm[ch * 66 + qq * 16 + t];
        sm[MU_ + qq * 16 + ch] = s;
    }
    __syncthreads();
    if (tid < 16) {
        float mval = (sm[MU_ + tid] + sm[MU_ + 16 + tid] + sm[MU_ + 32 + tid] + sm[MU_ + 48 + tid]) * (1.f / 64.f);
        sm[MU_ + tid] = mval;
    }
    __syncthreads();

    #pragma unroll
    for (int e = 0; e < 2; ++e) {
        int idx = tid * 2 + e;
        int s = idx >> 3, h = idx & 7;
        float a = sm[(2 * h) * 66 + s] - sm[MU_ + 2 * h];
        float c = sm[(2 * h + 1) * 66 + s] - sm[MU_ + 2 * h + 1];
        *(h2f*)&sm[FQP + s * 9 + h] = __builtin_amdgcn_cvt_pkrtz(a, c);
    }
    __syncthreads();

    const int g3 = tid & 7, m3 = tid >> 3;
    #pragma unroll 1
    for (int h = 0; h < 8; ++h) {
        const float mu0 = sm[MU_ + 2 * h], mu1 = sm[MU_ + 2 * h + 1];
        float fq0c[2], fq1c[2], pq0[2], pq1[2];
        #pragma unroll
        for (int js = 0; js < 2; ++js) {
            int s = 2 * m3 + js;
            h2f fq2 = *(const h2f*)&sm[FQP + s * 9 + h];
            h2f pq2 = *(const h2f*)&sm[PQP + s * 9 + h];
            fq0c[js] = (float)fq2.x; fq1c[js] = (float)fq2.y;
            pq0[js] = (float)pq2.x;  pq1[js] = (float)pq2.y;
        }
        float ao00 = 0.f, ao01 = 0.f, ao10 = 0.f, ao11 = 0.f;
        #pragma unroll
        for (int ch = 0; ch < 2; ++ch) {
            float fk0[4], fk1[4], pk0[4], pk1[4], fv0[4], fv1[4], un[4];
            #pragma unroll
            for (int j = 0; j < 4; ++j) {
                int t = 8 * g3 + ch * 4 + j;
                h2f fk2 = *(const h2f*)&sm[FKP + t * 9 + h];
                h2f pk2 = *(const h2f*)&sm[PKP + t * 9 + h];
                h2f fv2 = *(const h2f*)&sm[FVP + t * 9 + h];
                fk0[j] = (float)fk2.x; fk1[j] = (float)fk2.y;
                pk0[j] = (float)pk2.x; pk1[j] = (float)pk2.y;
                fv0[j] = (float)fv2.x; fv1[j] = (float)fv2.y;
                un[j] = mu0 * fk0[j] + mu1 * fk1[j];
            }
            #pragma unroll
            for (int js = 0; js < 2; ++js) {
                #pragma unroll
                for (int j = 0; j < 4; ++j) {
                    float lp = pq0[js] * pk0[j] + pq1[js] * pk1[j];
                    float a1 = fq0c[js] * fk0[j] + fq1c[js] * fk1[j] + lp;
                    float a2 = un[j] + lp;
                    float w = tanh_scaled(a1) + tanh_scaled(a2);
                    if (js == 0) { ao00 += w * fv0[j]; ao01 += w * fv1[j]; }
                    else         { ao10 += w * fv0[j]; ao11 += w * fv1[j]; }
                }
            }
        }
        #pragma unroll
        for (int off = 1; off <= 4; off <<= 1) {
            ao00 += __shfl_xor(ao00, off);
            ao01 += __shfl_xor(ao01, off);
            ao10 += __shfl_xor(ao10, off);
            ao11 += __shfl_xor(ao11, off);
        }
        if (g3 == 0) {
            sm[AO + (2 * m3) * 20 + 2 * h]         = ao00;
            sm[AO + (2 * m3) * 20 + 2 * h + 1]     = ao01;
            sm[AO + (2 * m3 + 1) * 20 + 2 * h]     = ao10;
            sm[AO + (2 * m3 + 1) * 20 + 2 * h + 1] = ao11;
        }
    }
    __syncthreads();

    const int t = tid & 63, oq = tid >> 6;
    float aorow[16];
    #pragma unroll
    for (int i = 0; i < 4; ++i)
        *(float4*)&aorow[i * 4] = *(const float4*)&sm[AO + t * 20 + i * 4];
    float* aop = aoc + (n * 25 + v) * 1024;
    #pragma unroll
    for (int j = 0; j < 4; ++j) {
        int o = oq * 4 + j;
        float acc4 = attn_b[o];
        #pragma unroll
        for (int c = 0; c < 16; ++c) acc4 += attn_w[o * 16 + c] * aorow[c];
        aop[o * 64 + t] = acc4;
        float ssum = acc4;
        #pragma unroll
        for (int off = 32; off >= 1; off >>= 1) ssum += __shfl_down(ssum, off, 64);
        if ((tid & 63) == 0) atomicAdd(&se[n * 64 + 48 + o], ssum);
    }
}

// ---------------------------------------------------------------------------
// K2: tcn MFMA. NEW epilogue: conv+bias staged in LDS (osl overlays xsl,
// stride 402 -> q-lanes conflict-free), then cooperative float2 pass writes
// out rows (1600B contiguous) with residual x added — no 64B scatter.
// se gets conv+bias only (x-sums come from transpose now).
// ---------------------------------------------------------------------------
__global__ __launch_bounds__(512, 1) void tcn_mfma_kernel(
    const float* __restrict__ x, const ushort* __restrict__ wb,
    const float* __restrict__ tcn_b, const float* __restrict__ tg,
    const float* __restrict__ tb, float* __restrict__ out, float* __restrict__ se)
{
    __shared__ ushort xsl[600 * 72];
    const int b = blockIdx.x;
    const int n = b >> 2, tile = b & 3;
    const int t0 = tile * 16;
    const int tid = threadIdx.x;

    for (int idx = tid; idx < 64 * 600; idx += 512) {
        int ci = idx / 600, r = idx - ci * 600;
        int tg_ = t0 - 4 + r / 25;
        int v = r % 25;
        float val = (tg_ >= 0 && tg_ < 64) ? x[((n * 64 + ci) * 64 + tg_) * 25 + v] : 0.f;
        xsl[r * 72 + ci] = f2bf(val);
    }
    __syncthreads();

    const int lane = tid & 63, wave = tid >> 6;
    const int m16 = lane & 15, q = lane >> 4;
    const int nt0 = wave * 3;

    f32x4 acc[3][3];
    f32x4 acc24[3];
    #pragma unroll
    for (int i = 0; i < 3; ++i)
        #pragma unroll
        for (int mt = 0; mt < 3; ++mt)
            acc[i][mt] = (f32x4){0.f, 0.f, 0.f, 0.f};
    #pragma unroll
    for (int mt = 0; mt < 3; ++mt) acc24[mt] = (f32x4){0.f, 0.f, 0.f, 0.f};

    for (int ktile = 0; ktile < 18; ++ktile) {
        const int kt = ktile >> 1;
        const int cib = (ktile & 1) * 32 + q * 8;
        bf16x8 afr[3];
        #pragma unroll
        for (int mt = 0; mt < 3; ++mt)
            afr[mt] = *(const bf16x8*)&wb[(mt * 16 + m16) * 576 + ktile * 32 + q * 8];
        #pragma unroll
        for (int i = 0; i < 3; ++i) {
            int p = (nt0 + i) * 16 + m16;
            bf16x8 bfr = *(const bf16x8*)&xsl[(p + kt * 25) * 72 + cib];
            #pragma unroll
            for (int mt = 0; mt < 3; ++mt)
                acc[i][mt] = __builtin_amdgcn_mfma_f32_16x16x32_bf16(afr[mt], bfr, acc[i][mt], 0, 0, 0);
        }
        if (wave == 0) {
            int p = 24 * 16 + m16;
            bf16x8 bfr = *(const bf16x8*)&xsl[(p + kt * 25) * 72 + cib];
            #pragma unroll
            for (int mt = 0; mt < 3; ++mt)
                acc24[mt] = __builtin_amdgcn_mfma_f32_16x16x32_bf16(afr[mt], bfr, acc24[mt], 0, 0, 0);
        }
    }
    __syncthreads();                 // all xsl reads done -> reuse as osl
    float* osl = (float*)xsl;        // [48][402] fp32, 77.2 KB <= 86.4 KB

    const float rsbn = rsqrtf(1.f + 1e-5f);
    float bias3[3][4], ssum[3][4];
    #pragma unroll
    for (int mt = 0; mt < 3; ++mt)
        #pragma unroll
        for (int r = 0; r < 4; ++r) {
            int oc = mt * 16 + q * 4 + r;
            bias3[mt][r] = tcn_b[oc] * (tg[oc] * rsbn) + tb[oc];
            ssum[mt][r] = 0.f;
        }
    #pragma unroll
    for (int i = 0; i < 3; ++i) {
        int pos = (nt0 + i) * 16 + m16;
        #pragma unroll
        for (int mt = 0; mt < 3; ++mt) {
            #pragma unroll
            for (int r = 0; r < 4; ++r) {
                float val = acc[i][mt][r] + bias3[mt][r];
                osl[(mt * 16 + q * 4 + r) * 402 + pos] = val;
                ssum[mt][r] += val;
            }
        }
    }
    if (wave == 0) {
        int pos = 24 * 16 + m16;
        #pragma unroll
        for (int mt = 0; mt < 3; ++mt) {
            #pragma unroll
            for (int r = 0; r < 4; ++r) {
                float val = acc24[mt][r] + bias3[mt][r];
                osl[(mt * 16 + q * 4 + r) * 402 + pos] = val;
                ssum[mt][r] += val;
            }
        }
    }
    #pragma unroll
    for (int mt = 0; mt < 3; ++mt) {
        #pragma unroll
        for (int r = 0; r < 4; ++r) {
            float s = ssum[mt][r];
            #pragma unroll
            for (int off = 1; off <= 8; off <<= 1) s += __shfl_xor(s, off);
            if (m16 == 0) {
                int oc = mt * 16 + q * 4 + r;
                atomicAdd(&se[n * 64 + oc], s);
            }
        }
    }
    __syncthreads();
    // cooperative pass: full-row out writes + residual
    for (int i = tid; i < 9600; i += 512) {
        int oc = i / 200, p2 = i - oc * 200;
        float2 cv = *(float2*)&osl[oc * 402 + p2 * 2];
        int g = (n * 64 + oc) * TV_ + tile * 400 + p2 * 2;
        float2 xr = *(const float2*)&x[g];
        cv.x += xr.x; cv.y += xr.y;
        *(float2*)&out[g] = cv;
    }
}

// ---------------------------------------------------------------------------
// K4: assemble + inline SE-gate MLP + BN + relu. Each block (100 blocks per n)
// recomputes its n's 64-channel gate (~4K FMA, weights L2-hot) — gate_kernel
// dispatch eliminated.
// ---------------------------------------------------------------------------
__global__ __launch_bounds__(256) void final_kernel(
    float* __restrict__ out, const float* __restrict__ aoc,
    const float* __restrict__ x, const float* __restrict__ se,
    const float* __restrict__ fc1w, const float* __restrict__ fc1b,
    const float* __restrict__ fc2w, const float* __restrict__ fc2b,
    const float* __restrict__ bng, const float* __restrict__ bnb)
{
    __shared__ float seL[64], hid[32], gateL[64];
    const int tid = threadIdx.x;
    const int n = blockIdx.x / 100;
    if (tid < 64) seL[tid] = se[n * 64 + tid] * (1.f / (float)TV_);
    __syncthreads();
    if (tid < 32) {
        float a = fc1b[tid];
        #pragma unroll
        for (int c = 0; c < 64; ++c) a += fc1w[tid * 64 + c] * seL[c];
        hid[tid] = fmaxf(a, 0.f);
    }
    __syncthreads();
    if (tid < 64) {
        float g = fc2b[tid];
        #pragma unroll
        for (int j = 0; j < 32; ++j) g += fc2w[tid * 32 + j] * hid[j];
        gateL[tid] = 1.f / (1.f + __expf(-g));
    }
    __syncthreads();

    const float rs = rsqrtf(1.f + 1e-5f);
    int idx4 = blockIdx.x * 256 + tid;
    int nc = idx4 / 400;
    int c = nc & 63;
    float4 val;
    if (c < 48) {
        val = ((const float4*)out)[idx4];
    } else {
        int rem = idx4 - nc * 400;
        const float* ap = aoc + n * 25600 + (c - 48) * 64;
        #pragma unroll
        for (int e = 0; e < 4; ++e) {
            int pos = rem * 4 + e;
            int t = pos / 25, v = pos - t * 25;
            ((float*)&val)[e] = ap[v * 1024 + t];
        }
        float4 xr = ((const float4*)x)[idx4];
        val.x += xr.x; val.y += xr.y; val.z += xr.z; val.w += xr.w;
    }
    float mm = (1.f + gateL[c]) * (bng[c] * rs);
    float bb = bnb[c];
    val.x = fmaxf(val.x * mm + bb, 0.f);
    val.y = fmaxf(val.y * mm + bb, 0.f);
    val.z = fmaxf(val.z * mm + bb, 0.f);
    val.w = fmaxf(val.w * mm + bb, 0.f);
    ((float4*)out)[idx4] = val;
}

extern "C" void kernel_launch(void* const* d_in, const int* in_sizes, int n_in,
                              void* d_out, int out_size, void* d_ws, size_t ws_size,
                              hipStream_t stream) {
    const float* x     = (const float*)d_in[0];
    const float* pe    = (const float*)d_in[1];
    const float* dbg   = (const float*)d_in[2];
    const float* dbb   = (const float*)d_in[3];
    const float* qkvw  = (const float*)d_in[4];
    const float* qkvb  = (const float*)d_in[5];
    const float* attnw = (const float*)d_in[6];
    const float* attnb = (const float*)d_in[7];
    const float* tcnw  = (const float*)d_in[8];
    const float* tcnb  = (const float*)d_in[9];
    const float* tcng  = (const float*)d_in[10];
    const float* tcnbb = (const float*)d_in[11];
    const float* fc1w  = (const float*)d_in[12];
    const float* fc1b  = (const float*)d_in[13];
    const float* fc2w  = (const float*)d_in[14];
    const float* fc2b  = (const float*)d_in[15];
    const float* bng   = (const float*)d_in[16];
    const float* bnb   = (const float*)d_in[17];

    float* out  = (float*)d_out;
    float* se   = (float*)d_ws;                      // 4096 f
    float* qb   = se + 4096;                         // 96 f
    float* aoc  = qb + 96;                           // 1,638,400 f
    ushort* wb  = (ushort*)(aoc + 1638400);          // 27648 u16
    ushort* wq  = wb + 27648;                        // 5120 u16
    ushort* xt  = wq + 5120;                         // 6,553,600 u16
    ushort* yt  = xt + 6553600;                      // 6,553,600 u16

    hipMemsetAsync(se, 0, 4096 * sizeof(float), stream);
    transpose_kernel<<<dim3(26, 64), dim3(256), 0, stream>>>(
        x, pe, dbg, dbb, tcnw, tcng, qkvw, qkvb, xt, yt, se, wb, wq, qb);
    score_kernel<<<dim3(1600), dim3(256), 0, stream>>>(xt, yt, wq, qb, attnw, attnb, aoc, se);
    tcn_mfma_kernel<<<dim3(256), dim3(512), 0, stream>>>(x, wb, tcnb, tcng, tcnbb, out, se);
    final_kernel<<<dim3(6400), dim3(256), 0, stream>>>(out, aoc, x, se, fc1w, fc1b, fc2w, fc2b, bng, bnb);
}

// Round 11
// 209.762 us; speedup vs baseline: 1.2294x; 1.2294x over previous
//
#include <hip/hip_runtime.h>
#include <hip/hip_bf16.h>
#include <math.h>

#define TV_ 1600
#define SCALE_K 2.885390081777927f   // 2*log2(e): folded into fk/pk rows so tanh uses exp2 directly
#define RS2_ 0.70710678118654752f    // DKH^-0.5 folded into fq/pq rows

typedef __attribute__((ext_vector_type(8))) short bf16x8;
typedef __attribute__((ext_vector_type(4))) float f32x4;
typedef __attribute__((ext_vector_type(2))) __fp16 h2f;

__device__ __forceinline__ float tanh_scaled(float y) {
    y = fminf(44.f, fmaxf(-44.f, y));
    float e = __builtin_amdgcn_exp2f(y);
    float r = __builtin_amdgcn_rcpf(e + 1.f);
    return __builtin_fmaf(e, r, -r);
}

__device__ __forceinline__ ushort f2bf(float f) {
    __hip_bfloat16 h = __float2bfloat16(f);
    return *(ushort*)&h;
}
__device__ __forceinline__ float bf2f(ushort u) {
    uint w = ((uint)u) << 16;
    return __uint_as_float(w);
}

// ---------------------------------------------------------------------------
// prep: wb (tcn weights bn-folded bf16), wq (qkv weights scale-folded bf16),
//       qb (qkv bias scale-folded fp32), pet[tv][ci] = bf16(pe) transposed.
// ---------------------------------------------------------------------------
__global__ __launch_bounds__(256) void prep_kernel(
    const float* __restrict__ tcn_w, const float* __restrict__ tg,
    const float* __restrict__ qkv_w, const float* __restrict__ qkv_b,
    const float* __restrict__ pe,
    ushort* __restrict__ wb, ushort* __restrict__ wq, float* __restrict__ qb,
    ushort* __restrict__ pet)
{
    int idx = blockIdx.x * 256 + threadIdx.x;
    if (idx < 27648) {
        int oc = idx / 576, kk = idx - oc * 576;
        int kt = kk >> 6, ci = kk & 63;
        float a = tg[oc] * rsqrtf(1.f + 1e-5f);
        wb[idx] = f2bf(tcn_w[(oc * 64 + ci) * 9 + kt] * a);
    } else if (idx < 32768) {
        int i2 = idx - 27648;
        int r = i2 >> 6, c = i2 & 63;
        int src; float sc;
        if (r < 16)      { src = r;      sc = RS2_; }
        else if (r < 32) { src = r;      sc = SCALE_K; }
        else if (r < 48) { src = r + 16; sc = 1.f; }
        else if (r < 64) { src = r - 48; sc = RS2_; }
        else             { src = r - 48; sc = SCALE_K; }
        wq[i2] = f2bf(qkv_w[src * 64 + c] * sc);
    } else if (idx < 32848) {
        int r = idx - 32768;
        int src; float sc;
        if (r < 16)      { src = r;      sc = RS2_; }
        else if (r < 32) { src = r;      sc = SCALE_K; }
        else if (r < 48) { src = r + 16; sc = 1.f; }
        else if (r < 64) { src = r - 48; sc = RS2_; }
        else             { src = r - 48; sc = SCALE_K; }
        qb[r] = qkv_b[src] * sc;
    } else if (idx < 32848 + 102400) {
        int i3 = idx - 32848;
        int ci = i3 / 1600, tv = i3 - ci * 1600;     // coalesced pe read
        pet[tv * 64 + ci] = f2bf(pe[ci * 1600 + tv]); // scattered 2B write, L2-merged
    }
}

// ---------------------------------------------------------------------------
// transpose: rt[n][tv][ci] = bf16(x) via LDS tile transpose (stride 66 odd ->
// conflict-free), + se[n][48..63] += sum_tv x. grid (25, 64).
// ---------------------------------------------------------------------------
__global__ __launch_bounds__(256) void transpose_kernel(
    const float* __restrict__ x, ushort* __restrict__ rt, float* __restrict__ se)
{
    __shared__ ushort smt[64 * 66];
    const int tid = threadIdx.x;
    const int tv0 = blockIdx.x * 64;
    const int n = blockIdx.y;
    const int tvl = tid & 63, cig = tid >> 6;
    const int tv = tv0 + tvl;

    float psum[4] = {0.f, 0.f, 0.f, 0.f};
    #pragma unroll
    for (int k = 0; k < 16; ++k) {
        int ci = k * 4 + cig;
        float xv = x[(n * 64 + ci) * TV_ + tv];
        smt[tvl * 66 + ci] = f2bf(xv);
        if (k >= 12) psum[k - 12] += xv;
    }
    #pragma unroll
    for (int j = 0; j < 4; ++j) {
        float s = psum[j];
        #pragma unroll
        for (int off = 32; off >= 1; off >>= 1) s += __shfl_down(s, off, 64);
        if (tvl == 0) atomicAdd(&se[n * 64 + 48 + j * 4 + cig], s);
    }
    __syncthreads();

    #pragma unroll
    for (int j = 0; j < 8; ++j) {
        int chunk = tid + j * 256;          // 2048 uints
        int tvr = chunk >> 5, p = chunk & 31;
        uint val = *(const uint*)&smt[tvr * 66 + p * 2];
        *(uint*)&rt[(n * TV_ + tv0 + tvr) * 64 + p * 2] = val;
    }
}

// ---------------------------------------------------------------------------
// K1: score kernel per (n,v). Phase 1 rebuilds xn=bn(x), yb=x+pe in registers
// from rt + pet (uint4 loads). Rest unchanged from round 9 (59 us isolated).
// ---------------------------------------------------------------------------
__global__ __launch_bounds__(256, 5) void score_kernel(
    const ushort* __restrict__ rt, const ushort* __restrict__ pet,
    const float* __restrict__ dbg, const float* __restrict__ dbb,
    const ushort* __restrict__ wq, const float* __restrict__ qb,
    const float* __restrict__ attn_w, const float* __restrict__ attn_b,
    float* __restrict__ aoc, float* __restrict__ se)
{
    __shared__ float sm[5312];
    ushort* smu = (ushort*)sm;
    const int MU_ = 1056, AO = 1120;
    const int FKP = 2400, PKP = 2976, FVP = 3552, PQP = 4128, FQP = 4704;

    const int b = blockIdx.x;
    const int l = b >> 3;
    const int n = (b & 7) * 8 + l / 25;
    const int v = l % 25;
    const int tid = threadIdx.x;

    const int lane = tid & 63, wave = tid >> 6;
    const int m16 = lane & 15, q = lane >> 4;

    // phase 1: build xn/yb bf16 planes from rt + pet
    {
        const int part = tid & 7;
        const int ci0 = part * 8;
        const float rs = rsqrtf(1.f + 1e-5f);
        float sc8[8], sh8[8];
        #pragma unroll
        for (int i = 0; i < 8; ++i) {
            sc8[i] = dbg[(ci0 + i) * 25 + v] * rs;
            sh8[i] = dbb[(ci0 + i) * 25 + v];
        }
        #pragma unroll
        for (int j = 0; j < 2; ++j) {
            int t = (tid + j * 256) >> 3;
            uint4 xr = *(const uint4*)&rt[(n * TV_ + t * 25 + v) * 64 + ci0];
            uint4 pr = *(const uint4*)&pet[(t * 25 + v) * 64 + ci0];
            const ushort* xu = (const ushort*)&xr;
            const ushort* pu = (const ushort*)&pr;
            ushort xs[8], ys[8];
            #pragma unroll
            for (int i = 0; i < 8; ++i) {
                float xf = bf2f(xu[i]);
                xs[i] = f2bf(xf * sc8[i] + sh8[i]);
                ys[i] = f2bf(xf + bf2f(pu[i]));
            }
            *(uint4*)&smu[t * 72 + ci0] = *(uint4*)xs;
            *(uint4*)&smu[4608 + t * 72 + ci0] = *(uint4*)ys;
        }
    }
    __syncthreads();

    // phase 2: qkv MFMA
    f32x4 acc[5];
    #pragma unroll
    for (int mt = 0; mt < 5; ++mt) acc[mt] = (f32x4){0.f, 0.f, 0.f, 0.f};
    #pragma unroll
    for (int kt = 0; kt < 2; ++kt) {
        const int koff = kt * 32 + q * 8;
        bf16x8 bx = *(const bf16x8*)&smu[(wave * 16 + m16) * 72 + koff];
        bf16x8 by = *(const bf16x8*)&smu[4608 + (wave * 16 + m16) * 72 + koff];
        #pragma unroll
        for (int mt = 0; mt < 5; ++mt) {
            bf16x8 a = *(const bf16x8*)&wq[(mt * 16 + m16) * 64 + koff];
            acc[mt] = __builtin_amdgcn_mfma_f32_16x16x32_bf16(a, (mt < 3) ? bx : by, acc[mt], 0, 0, 0);
        }
    }
    __syncthreads();

    // phase 2b: FQ32 fp32 plane + packed f16x2 planes (bias folded)
    {
        const int t = wave * 16 + m16;
        #pragma unroll
        for (int r = 0; r < 4; ++r)
            sm[(q * 4 + r) * 66 + t] = acc[0][r] + qb[q * 4 + r];
        *(h2f*)&sm[FKP + t * 9 + 2 * q] =
            __builtin_amdgcn_cvt_pkrtz(acc[1][0] + qb[16 + q * 4], acc[1][1] + qb[16 + q * 4 + 1]);
        *(h2f*)&sm[FKP + t * 9 + 2 * q + 1] =
            __builtin_amdgcn_cvt_pkrtz(acc[1][2] + qb[16 + q * 4 + 2], acc[1][3] + qb[16 + q * 4 + 3]);
        *(h2f*)&sm[FVP + t * 9 + 2 * q] =
            __builtin_amdgcn_cvt_pkrtz(acc[2][0] + qb[32 + q * 4], acc[2][1] + qb[32 + q * 4 + 1]);
        *(h2f*)&sm[FVP + t * 9 + 2 * q + 1] =
            __builtin_amdgcn_cvt_pkrtz(acc[2][2] + qb[32 + q * 4 + 2], acc[2][3] + qb[32 + q * 4 + 3]);
        *(h2f*)&sm[PQP + t * 9 + 2 * q] =
            __builtin_amdgcn_cvt_pkrtz(acc[3][0] + qb[48 + q * 4], acc[3][1] + qb[48 + q * 4 + 1]);
        *(h2f*)&sm[PQP + t * 9 + 2 * q + 1] =
            __builtin_amdgcn_cvt_pkrtz(acc[3][2] + qb[48 + q * 4 + 2], acc[3][3] + qb[48 + q * 4 + 3]);
        *(h2f*)&sm[PKP + t * 9 + 2 * q] =
            __builtin_amdgcn_cvt_pkrtz(acc[4][0] + qb[64 + q * 4], acc[4][1] + qb[64 + q * 4 + 1]);
        *(h2f*)&sm[PKP + t * 9 + 2 * q + 1] =
            __builtin_amdgcn_cvt_pkrtz(acc[4][2] + qb[64 + q * 4 + 2], acc[4][3] + qb[64 + q * 4 + 3]);
    }
    __syncthreads();

    // mu over t for the 16 fq channels
    if (tid < 64) {
        int ch = tid & 15, qq = tid >> 4;
        float s = 0.f;
        #pragma unroll
        for (int t = 0; t < 16; ++t) s += sm[ch * 66 + qq * 16 + t];
        sm[MU_ + qq * 16 + ch] = s;
    }
    __syncthreads();
    if (tid < 16) {
        float mval = (sm[MU_ + tid] + sm[MU_ + 16 + tid] + sm[MU_ + 32 + tid] + sm[MU_ + 48 + tid]) * (1.f / 64.f);
        sm[MU_ + tid] = mval;
    }
    __syncthreads();

    // fqc pack mini-phase
    #pragma unroll
    for (int e = 0; e < 2; ++e) {
        int idx = tid * 2 + e;
        int s = idx >> 3, h = idx & 7;
        float a = sm[(2 * h) * 66 + s] - sm[MU_ + 2 * h];
        float c = sm[(2 * h + 1) * 66 + s] - sm[MU_ + 2 * h + 1];
        *(h2f*)&sm[FQP + s * 9 + h] = __builtin_amdgcn_cvt_pkrtz(a, c);
    }
    __syncthreads();

    // phase 3: per head; thread tile 2 s x 8 t
    const int g3 = tid & 7, m3 = tid >> 3;
    #pragma unroll 1
    for (int h = 0; h < 8; ++h) {
        const float mu0 = sm[MU_ + 2 * h], mu1 = sm[MU_ + 2 * h + 1];
        float fq0c[2], fq1c[2], pq0[2], pq1[2];
        #pragma unroll
        for (int js = 0; js < 2; ++js) {
            int s = 2 * m3 + js;
            h2f fq2 = *(const h2f*)&sm[FQP + s * 9 + h];
            h2f pq2 = *(const h2f*)&sm[PQP + s * 9 + h];
            fq0c[js] = (float)fq2.x; fq1c[js] = (float)fq2.y;
            pq0[js] = (float)pq2.x;  pq1[js] = (float)pq2.y;
        }
        float ao00 = 0.f, ao01 = 0.f, ao10 = 0.f, ao11 = 0.f;
        #pragma unroll
        for (int ch = 0; ch < 2; ++ch) {
            float fk0[4], fk1[4], pk0[4], pk1[4], fv0[4], fv1[4], un[4];
            #pragma unroll
            for (int j = 0; j < 4; ++j) {
                int t = 8 * g3 + ch * 4 + j;
                h2f fk2 = *(const h2f*)&sm[FKP + t * 9 + h];
                h2f pk2 = *(const h2f*)&sm[PKP + t * 9 + h];
                h2f fv2 = *(const h2f*)&sm[FVP + t * 9 + h];
                fk0[j] = (float)fk2.x; fk1[j] = (float)fk2.y;
                pk0[j] = (float)pk2.x; pk1[j] = (float)pk2.y;
                fv0[j] = (float)fv2.x; fv1[j] = (float)fv2.y;
                un[j] = mu0 * fk0[j] + mu1 * fk1[j];
            }
            #pragma unroll
            for (int js = 0; js < 2; ++js) {
                #pragma unroll
                for (int j = 0; j < 4; ++j) {
                    float lp = pq0[js] * pk0[j] + pq1[js] * pk1[j];
                    float a1 = fq0c[js] * fk0[j] + fq1c[js] * fk1[j] + lp;
                    float a2 = un[j] + lp;
                    float w = tanh_scaled(a1) + tanh_scaled(a2);
                    if (js == 0) { ao00 += w * fv0[j]; ao01 += w * fv1[j]; }
                    else         { ao10 += w * fv0[j]; ao11 += w * fv1[j]; }
                }
            }
        }
        #pragma unroll
        for (int off = 1; off <= 4; off <<= 1) {
            ao00 += __shfl_xor(ao00, off);
            ao01 += __shfl_xor(ao01, off);
            ao10 += __shfl_xor(ao10, off);
            ao11 += __shfl_xor(ao11, off);
        }
        if (g3 == 0) {
            sm[AO + (2 * m3) * 20 + 2 * h]         = ao00;
            sm[AO + (2 * m3) * 20 + 2 * h + 1]     = ao01;
            sm[AO + (2 * m3 + 1) * 20 + 2 * h]     = ao10;
            sm[AO + (2 * m3 + 1) * 20 + 2 * h + 1] = ao11;
        }
    }
    __syncthreads();

    // phase 4: attn_w proj; attn-only coalesced aoc write + se atomics
    const int t = tid & 63, oq = tid >> 6;
    float aorow[16];
    #pragma unroll
    for (int i = 0; i < 4; ++i)
        *(float4*)&aorow[i * 4] = *(const float4*)&sm[AO + t * 20 + i * 4];
    float* aop = aoc + (n * 25 + v) * 1024;
    #pragma unroll
    for (int j = 0; j < 4; ++j) {
        int o = oq * 4 + j;
        float acc4 = attn_b[o];
        #pragma unroll
        for (int c = 0; c < 16; ++c) acc4 += attn_w[o * 16 + c] * aorow[c];
        aop[o * 64 + t] = acc4;
        float ssum = acc4;
        #pragma unroll
        for (int off = 32; off >= 1; off >>= 1) ssum += __shfl_down(ssum, off, 64);
        if ((tid & 63) == 0) atomicAdd(&se[n * 64 + 48 + o], ssum);
    }
}

// ---------------------------------------------------------------------------
// K2: tcn MFMA. Staging = pure uint4 copies from rt (contiguous 76.8 KB/block;
// replaces 75 scalar-load+convert+conflicted-write iterations). Epilogue =
// round-9 form (scattered out+residual+se, L2-merged).
// ---------------------------------------------------------------------------
__global__ __launch_bounds__(512, 1) void tcn_mfma_kernel(
    const ushort* __restrict__ rt, const float* __restrict__ x,
    const ushort* __restrict__ wb,
    const float* __restrict__ tcn_b, const float* __restrict__ tg,
    const float* __restrict__ tb, float* __restrict__ out, float* __restrict__ se)
{
    __shared__ ushort xsl[600 * 72];
    const int b = blockIdx.x;
    const int n = b >> 2, tile = b & 3;
    const int t0 = tile * 16;
    const int tid = threadIdx.x;

    const int tvbase = (t0 - 4) * 25;
    for (int idx = tid; idx < 4800; idx += 512) {
        int r = idx >> 3, part = idx & 7;
        int tv = tvbase + r;
        uint4 val = make_uint4(0u, 0u, 0u, 0u);
        if (tv >= 0 && tv < TV_) val = *(const uint4*)&rt[(n * TV_ + tv) * 64 + part * 8];
        *(uint4*)&xsl[r * 72 + part * 8] = val;
    }
    __syncthreads();

    const int lane = tid & 63, wave = tid >> 6;
    const int m16 = lane & 15, q = lane >> 4;
    const int nt0 = wave * 3;

    f32x4 acc[3][3];
    f32x4 acc24[3];
    #pragma unroll
    for (int i = 0; i < 3; ++i)
        #pragma unroll
        for (int mt = 0; mt < 3; ++mt)
            acc[i][mt] = (f32x4){0.f, 0.f, 0.f, 0.f};
    #pragma unroll
    for (int mt = 0; mt < 3; ++mt) acc24[mt] = (f32x4){0.f, 0.f, 0.f, 0.f};

    for (int ktile = 0; ktile < 18; ++ktile) {
        const int kt = ktile >> 1;
        const int cib = (ktile & 1) * 32 + q * 8;
        bf16x8 afr[3];
        #pragma unroll
        for (int mt = 0; mt < 3; ++mt)
            afr[mt] = *(const bf16x8*)&wb[(mt * 16 + m16) * 576 + ktile * 32 + q * 8];
        #pragma unroll
        for (int i = 0; i < 3; ++i) {
            int p = (nt0 + i) * 16 + m16;
            bf16x8 bfr = *(const bf16x8*)&xsl[(p + kt * 25) * 72 + cib];
            #pragma unroll
            for (int mt = 0; mt < 3; ++mt)
                acc[i][mt] = __builtin_amdgcn_mfma_f32_16x16x32_bf16(afr[mt], bfr, acc[i][mt], 0, 0, 0);
        }
        if (wave == 0) {
            int p = 24 * 16 + m16;
            bf16x8 bfr = *(const bf16x8*)&xsl[(p + kt * 25) * 72 + cib];
            #pragma unroll
            for (int mt = 0; mt < 3; ++mt)
                acc24[mt] = __builtin_amdgcn_mfma_f32_16x16x32_bf16(afr[mt], bfr, acc24[mt], 0, 0, 0);
        }
    }

    const float rsbn = rsqrtf(1.f + 1e-5f);
    float bias3[3][4], ssum[3][4];
    #pragma unroll
    for (int mt = 0; mt < 3; ++mt)
        #pragma unroll
        for (int r = 0; r < 4; ++r) {
            int oc = mt * 16 + q * 4 + r;
            bias3[mt][r] = tcn_b[oc] * (tg[oc] * rsbn) + tb[oc];
            ssum[mt][r] = 0.f;
        }
    #pragma unroll
    for (int i = 0; i < 3; ++i) {
        int posg = tile * 400 + (nt0 + i) * 16 + m16;
        #pragma unroll
        for (int mt = 0; mt < 3; ++mt) {
            #pragma unroll
            for (int r = 0; r < 4; ++r) {
                int oc = mt * 16 + q * 4 + r;
                float val = acc[i][mt][r] + bias3[mt][r] + x[(n * 64 + oc) * TV_ + posg];
                out[(n * 64 + oc) * TV_ + posg] = val;
                ssum[mt][r] += val;
            }
        }
    }
    if (wave == 0) {
        int posg = tile * 400 + 24 * 16 + m16;
        #pragma unroll
        for (int mt = 0; mt < 3; ++mt) {
            #pragma unroll
            for (int r = 0; r < 4; ++r) {
                int oc = mt * 16 + q * 4 + r;
                float val = acc24[mt][r] + bias3[mt][r] + x[(n * 64 + oc) * TV_ + posg];
                out[(n * 64 + oc) * TV_ + posg] = val;
                ssum[mt][r] += val;
            }
        }
    }
    #pragma unroll
    for (int mt = 0; mt < 3; ++mt) {
        #pragma unroll
        for (int r = 0; r < 4; ++r) {
            float s = ssum[mt][r];
            #pragma unroll
            for (int off = 1; off <= 8; off <<= 1) s += __shfl_xor(s, off);
            if (m16 == 0) {
                int oc = mt * 16 + q * 4 + r;
                atomicAdd(&se[n * 64 + oc], s);
            }
        }
    }
}

// ---------------------------------------------------------------------------
// K3: SE gate MLP per n (round-9 form)
// ---------------------------------------------------------------------------
__global__ __launch_bounds__(64) void gate_kernel(
    const float* __restrict__ se,
    const float* __restrict__ fc1w, const float* __restrict__ fc1b,
    const float* __restrict__ fc2w, const float* __restrict__ fc2b,
    float* __restrict__ gate)
{
    const int n = blockIdx.x;
    const int tid = threadIdx.x;
    __shared__ float seL[64], hid[32];
    seL[tid] = se[n * 64 + tid] * (1.f / (float)TV_);
    __syncthreads();
    if (tid < 32) {
        float a = fc1b[tid];
        #pragma unroll
        for (int c = 0; c < 64; ++c) a += fc1w[tid * 64 + c] * seL[c];
        hid[tid] = fmaxf(a, 0.f);
    }
    __syncthreads();
    float gacc = fc2b[tid];
    #pragma unroll
    for (int j = 0; j < 32; ++j) gacc += fc2w[tid * 32 + j] * hid[j];
    gate[n * 64 + tid] = 1.f / (1.f + __expf(-gacc));
}

// ---------------------------------------------------------------------------
// K4: assemble + gate + BN + relu (round-9 form)
// ---------------------------------------------------------------------------
__global__ __launch_bounds__(256) void final_kernel(
    float* __restrict__ out, const float* __restrict__ aoc,
    const float* __restrict__ x, const float* __restrict__ gate,
    const float* __restrict__ bng, const float* __restrict__ bnb)
{
    const float rs = rsqrtf(1.f + 1e-5f);
    int idx4 = blockIdx.x * 256 + threadIdx.x;
    if (idx4 >= 1638400) return;
    int nc = idx4 / 400;
    int c = nc & 63, n = nc >> 6;
    float4 val;
    if (c < 48) {
        val = ((const float4*)out)[idx4];
    } else {
        int rem = idx4 - nc * 400;
        const float* ap = aoc + n * 25600 + (c - 48) * 64;
        #pragma unroll
        for (int e = 0; e < 4; ++e) {
            int pos = rem * 4 + e;
            int t = pos / 25, v = pos - t * 25;
            ((float*)&val)[e] = ap[v * 1024 + t];
        }
        float4 xr = ((const float4*)x)[idx4];
        val.x += xr.x; val.y += xr.y; val.z += xr.z; val.w += xr.w;
    }
    float mm = (1.f + gate[nc]) * (bng[c] * rs);
    float bb = bnb[c];
    val.x = fmaxf(val.x * mm + bb, 0.f);
    val.y = fmaxf(val.y * mm + bb, 0.f);
    val.z = fmaxf(val.z * mm + bb, 0.f);
    val.w = fmaxf(val.w * mm + bb, 0.f);
    ((float4*)out)[idx4] = val;
}

extern "C" void kernel_launch(void* const* d_in, const int* in_sizes, int n_in,
                              void* d_out, int out_size, void* d_ws, size_t ws_size,
                              hipStream_t stream) {
    const float* x     = (const float*)d_in[0];
    const float* pe    = (const float*)d_in[1];
    const float* dbg   = (const float*)d_in[2];
    const float* dbb   = (const float*)d_in[3];
    const float* qkvw  = (const float*)d_in[4];
    const float* qkvb  = (const float*)d_in[5];
    const float* attnw = (const float*)d_in[6];
    const float* attnb = (const float*)d_in[7];
    const float* tcnw  = (const float*)d_in[8];
    const float* tcnb  = (const float*)d_in[9];
    const float* tcng  = (const float*)d_in[10];
    const float* tcnbb = (const float*)d_in[11];
    const float* fc1w  = (const float*)d_in[12];
    const float* fc1b  = (const float*)d_in[13];
    const float* fc2w  = (const float*)d_in[14];
    const float* fc2b  = (const float*)d_in[15];
    const float* bng   = (const float*)d_in[16];
    const float* bnb   = (const float*)d_in[17];

    float* out  = (float*)d_out;
    float* se   = (float*)d_ws;                      // 4096 f
    float* gate = se + 4096;                         // 4096 f
    float* qb   = gate + 4096;                       // 96 f
    float* aoc  = qb + 96;                           // 1,638,400 f
    ushort* wb  = (ushort*)(aoc + 1638400);          // 27648 u16
    ushort* wq  = wb + 27648;                        // 5120 u16
    ushort* pet = wq + 5120;                         // 102,400 u16
    ushort* rt  = pet + 102400;                      // 6,553,600 u16

    hipMemsetAsync(se, 0, 4096 * sizeof(float), stream);
    prep_kernel<<<dim3(529), dim3(256), 0, stream>>>(tcnw, tcng, qkvw, qkvb, pe, wb, wq, qb, pet);
    transpose_kernel<<<dim3(25, 64), dim3(256), 0, stream>>>(x, rt, se);
    score_kernel<<<dim3(1600), dim3(256), 0, stream>>>(rt, pet, dbg, dbb, wq, qb, attnw, attnb, aoc, se);
    tcn_mfma_kernel<<<dim3(256), dim3(512), 0, stream>>>(rt, x, wb, tcnb, tcng, tcnbb, out, se);
    gate_kernel<<<dim3(64), dim3(64), 0, stream>>>(se, fc1w, fc1b, fc2w, fc2b, gate);
    final_kernel<<<dim3(6400), dim3(256), 0, stream>>>(out, aoc, x, gate, bng, bnb);
}